// Round 1
// baseline (164.138 us; speedup 1.0000x reference)
//
#include <hip/hip_runtime.h>

#define BATCH 32
#define I_TOT 4096
#define N_CAP 16
#define D_CAP 16
#define K_DIM 128
#define CHUNK 256
#define NCHUNK (I_TOT / CHUNK)  // 16

// ws layout (floats):
//   colsum: [B][128]        off 0       size 4096
//   w_o:    [B][16][128]    off 4096    size 65536
//   s:      [B][16][128]    off 69632   size 65536
// total 135168 floats = 540,672 bytes
#define WS_COLSUM 0
#define WS_WO 4096
#define WS_S 69632
#define WS_TOTAL 135168

// ---------------------------------------------------------------------------
// K1: colsum[b][k] = sum_i u[b,i,k]
// grid (8, 32), block 256. Each block: 512 rows of batch b.
__global__ __launch_bounds__(256) void colsum_kernel(const float* __restrict__ u,
                                                     float* __restrict__ ws) {
    const int b = blockIdx.y;
    const int chunk = blockIdx.x;       // 0..7, 512 rows each
    const int k = threadIdx.x & 127;
    const int h = threadIdx.x >> 7;     // 0/1
    const float* up = u + ((size_t)b * I_TOT + chunk * 512 + h * 256) * K_DIM + k;
    float acc = 0.f;
    #pragma unroll 4
    for (int i = 0; i < 256; i++) acc += up[(size_t)i * K_DIM];
    atomicAdd(&ws[WS_COLSUM + b * K_DIM + k], acc);
}

// ---------------------------------------------------------------------------
// K2: from src (colsum/16 or s) compute o[b,n,d]; then either
//   mode 0: init   — o = colsum-proj/16, l2-normalize, write w_o, zero s
//   mode 1: middle — o = s-proj,         l2-normalize, write w_o, zero s
//   mode 2: final  — o = s-proj, squash, write d_out
// grid 32 (one block per b), block 256 (t = n*16+d).
__global__ __launch_bounds__(256) void update_kernel(const float* __restrict__ W,
                                                     float* __restrict__ ws,
                                                     float* __restrict__ out,
                                                     int mode) {
    const int b = blockIdx.x;
    const int t = threadIdx.x;
    const int n = t >> 4;
    const int d = t & 15;
    const int col = n * 16 + d;

    float* w_o = ws + WS_WO;
    float* s = ws + WS_S;

    __shared__ __align__(16) float o_s[N_CAP][D_CAP];

    const float* src = (mode == 0) ? (ws + WS_COLSUM + b * K_DIM)
                                   : (s + ((size_t)b * N_CAP + n) * K_DIM);
    float o = 0.f;
    for (int k = 0; k < K_DIM; k++) o += src[k] * W[k * 256 + col];
    if (mode == 0) o *= (1.f / 16.f);

    o_s[n][d] = o;
    __syncthreads();

    if (mode == 2) {
        float ss = 1e-7f;  // EPS
        #pragma unroll
        for (int j = 0; j < 16; j++) { float v = o_s[n][j]; ss += v * v; }
        float scale = sqrtf(ss) / (0.5f + ss);
        out[b * 256 + col] = scale * o;
        return;
    }

    // l2 normalize over d
    float ss = 0.f;
    #pragma unroll
    for (int j = 0; j < 16; j++) { float v = o_s[n][j]; ss += v * v; }
    float on = o * rsqrtf(fmaxf(ss, 1e-12f));
    __syncthreads();
    o_s[n][d] = on;
    __syncthreads();

    // w_o[b][nn][k] = sum_d W[k][nn*16+d] * o_s[nn][d]; 2048 entries, 8/thread
    #pragma unroll
    for (int j = 0; j < 8; j++) {
        int idx = t + j * 256;      // 0..2047
        int nn = idx >> 7;
        int k = idx & 127;
        const float* wrow = W + k * 256 + nn * 16;
        float acc = 0.f;
        #pragma unroll
        for (int dd = 0; dd < 16; dd++) acc += wrow[dd] * o_s[nn][dd];
        w_o[((size_t)b * N_CAP + nn) * K_DIM + k] = acc;
    }
    // zero s for next routing pass
    #pragma unroll
    for (int j = 0; j < 8; j++) {
        s[(size_t)b * 2048 + t + j * 256] = 0.f;
    }
}

// ---------------------------------------------------------------------------
// K3: one routing pass. For each row i: logits_n = u_i . w_o[b,n,:],
// softmax over n, then s[b,n,k] += c_n * u_i[k].
// grid (16, 32), block 256 (one row per thread in phase 1).
__global__ __launch_bounds__(256) void routing_kernel(const float* __restrict__ u,
                                                      float* __restrict__ ws) {
    const int b = blockIdx.y;
    const int i0 = blockIdx.x * CHUNK;
    const int t = threadIdx.x;

    float* w_o = ws + WS_WO;
    float* s = ws + WS_S;

    __shared__ __align__(16) float wo_s[N_CAP][K_DIM];   // 8 KiB
    __shared__ __align__(16) float c_s[CHUNK][N_CAP];    // 16 KiB

    // cooperative load of w_o[b] (2048 floats)
    #pragma unroll
    for (int j = 0; j < 8; j++) {
        int idx = t + j * 256;
        ((float*)wo_s)[idx] = w_o[(size_t)b * 2048 + idx];
    }
    __syncthreads();

    // ---- phase 1: one row per thread ----
    const float4* up = (const float4*)(u + ((size_t)(b * I_TOT + i0 + t)) * K_DIM);
    float logit[16];
    #pragma unroll
    for (int n = 0; n < 16; n++) logit[n] = 0.f;
    for (int q = 0; q < 32; q++) {
        float4 v = up[q];
        #pragma unroll
        for (int n = 0; n < 16; n++) {
            float4 w = ((const float4*)wo_s[n])[q];
            logit[n] += v.x * w.x + v.y * w.y + v.z * w.z + v.w * w.w;
        }
    }
    float m = logit[0];
    #pragma unroll
    for (int n = 1; n < 16; n++) m = fmaxf(m, logit[n]);
    float sum = 0.f;
    #pragma unroll
    for (int n = 0; n < 16; n++) { logit[n] = __expf(logit[n] - m); sum += logit[n]; }
    float inv = 1.f / sum;
    float4* crow = (float4*)c_s[t];
    crow[0] = make_float4(logit[0] * inv, logit[1] * inv, logit[2] * inv, logit[3] * inv);
    crow[1] = make_float4(logit[4] * inv, logit[5] * inv, logit[6] * inv, logit[7] * inv);
    crow[2] = make_float4(logit[8] * inv, logit[9] * inv, logit[10] * inv, logit[11] * inv);
    crow[3] = make_float4(logit[12] * inv, logit[13] * inv, logit[14] * inv, logit[15] * inv);
    __syncthreads();

    // ---- phase 2: k-parallel accumulation of s ----
    const int k = t & 127;
    const int nh = t >> 7;  // n base = nh*8
    float acc[8];
    #pragma unroll
    for (int j = 0; j < 8; j++) acc[j] = 0.f;
    const float* ub = u + ((size_t)(b * I_TOT + i0)) * K_DIM + k;
    for (int i = 0; i < CHUNK; i++) {
        float uv = ub[(size_t)i * K_DIM];
        const float4* c4 = (const float4*)&c_s[i][nh * 8];
        float4 c0 = c4[0], c1 = c4[1];
        acc[0] += uv * c0.x; acc[1] += uv * c0.y;
        acc[2] += uv * c0.z; acc[3] += uv * c0.w;
        acc[4] += uv * c1.x; acc[5] += uv * c1.y;
        acc[6] += uv * c1.z; acc[7] += uv * c1.w;
    }
    #pragma unroll
    for (int j = 0; j < 8; j++)
        atomicAdd(&s[(size_t)b * 2048 + (nh * 8 + j) * K_DIM + k], acc[j]);
}

// ---------------------------------------------------------------------------
extern "C" void kernel_launch(void* const* d_in, const int* in_sizes, int n_in,
                              void* d_out, int out_size, void* d_ws, size_t ws_size,
                              hipStream_t stream) {
    const float* u = (const float*)d_in[0];   // (32, 4096, 128) f32
    const float* W = (const float*)d_in[1];   // (128, 256) f32
    float* out = (float*)d_out;               // (32, 16, 16) f32
    float* ws = (float*)d_ws;

    // zero colsum + s (w_o overwritten anyway)
    hipMemsetAsync(ws, 0, WS_TOTAL * sizeof(float), stream);

    dim3 g1(8, BATCH);
    colsum_kernel<<<g1, 256, 0, stream>>>(u, ws);

    // iter 0: uniform c -> o0 from colsum; normalize; w_o for iter 1
    update_kernel<<<BATCH, 256, 0, stream>>>(W, ws, out, 0);

    dim3 g3(NCHUNK, BATCH);
    for (int pass = 0; pass < 3; pass++) {
        routing_kernel<<<g3, 256, 0, stream>>>(u, ws);
        update_kernel<<<BATCH, 256, 0, stream>>>(W, ws, out, pass == 2 ? 2 : 1);
    }
}